// Round 21
// baseline (272.781 us; speedup 1.0000x reference)
//
#include <hip/hip_runtime.h>
#include <stdint.h>

// MultiHeadAttention fused pipeline for MI355X (gfx950).
// B=2, S=2048, D=1024, H=16, dk=64. fp32 in/out, bf16 MFMA compute.
// R21: R20 build (111.2us) + MODE0 retiled 128x64 -> 512 blocks/z =
// 6 co-resident blocks/CU (third application of the co-residency lever;
// K-accumulation order unchanged -> bitwise-identical output).

#define AS1 __attribute__((address_space(1)))
#define AS3 __attribute__((address_space(3)))

typedef unsigned short u16;
typedef short s16x8 __attribute__((ext_vector_type(8)));   // 8 bf16 (4 VGPRs) MFMA frag
typedef float f32x4 __attribute__((ext_vector_type(4)));   // 16x16 MFMA accumulator
typedef float f32x16 __attribute__((ext_vector_type(16))); // 32x32 MFMA accumulator
typedef u16   u16x4 __attribute__((ext_vector_type(4)));

#if defined(__has_builtin)
#if __has_builtin(__builtin_amdgcn_exp2f)
#define EXP2F(x) __builtin_amdgcn_exp2f(x)
#else
#define EXP2F(x) exp2f(x)
#endif
#else
#define EXP2F(x) exp2f(x)
#endif

// Counted-vmcnt barrier (T4): keeps the N newest vmem ops in flight across
// the barrier instead of __syncthreads()' full vmcnt(0) drain.
#define BARC(N)                                                               \
  do {                                                                        \
    __builtin_amdgcn_sched_barrier(0);                                        \
    asm volatile("s_waitcnt vmcnt(" #N ") lgkmcnt(0)" ::: "memory");          \
    __builtin_amdgcn_s_barrier();                                             \
    __builtin_amdgcn_sched_barrier(0);                                        \
  } while (0)

__device__ __forceinline__ u16 f2b(float f) {  // fp32 -> bf16 RNE
  union { float f; uint32_t u; } v;
  v.f = f;
  uint32_t r = (v.u + 0x7fffu + ((v.u >> 16) & 1u)) >> 16;
  return (u16)r;
}

// packed fp32x2 -> bf16x2 (1 VALU op; no builtin on gfx950 -> inline asm, T12)
__device__ __forceinline__ uint32_t cvtpk(float lo, float hi) {
  uint32_t r;
  asm("v_cvt_pk_bf16_f32 %0, %1, %2" : "=v"(r) : "v"(lo), "v"(hi));
  return r;
}

__device__ __forceinline__ float max3f(float a, float b, float c) {
  float r;
  asm("v_max3_f32 %0, %1, %2, %3" : "=v"(r) : "v"(a), "v"(b), "v"(c));
  return r;
}

__device__ __forceinline__ f32x4 mfma16(s16x8 a, s16x8 b, f32x4 c) {
  return __builtin_amdgcn_mfma_f32_16x16x32_bf16(a, b, c, 0, 0, 0);
}

__device__ __forceinline__ f32x16 mfma32(s16x8 a, s16x8 b, f32x16 c) {
  return __builtin_amdgcn_mfma_f32_32x32x16_bf16(a, b, c, 0, 0, 0);
}

__device__ __forceinline__ s16x8 ld_g16(const u16* p) {
  return *reinterpret_cast<const s16x8*>(p);
}

// async global->LDS, 16B per lane. LDS dest must be WAVE-UNIFORM base; HW adds lane*16.
// Global SOURCE is per-lane -> swizzled layouts via pre-swizzled source (m173).
__device__ __forceinline__ void stage16(const u16* g, u16* lds_base) {
  __builtin_amdgcn_global_load_lds((const AS1 unsigned int*)g,
                                   (AS3 unsigned int*)lds_base, 16, 0, 0);
}

// ---------------------------------------------------------------- fp32 -> bf16 (weights only)
struct CvtArgs {
  const float* src[4];
  u16* dst[4];
  int cum[5];   // cumulative block ranges (1024 blocks per 1M-elem weight)
};

__global__ __launch_bounds__(256) void cvt_all(CvtArgs a) {
  const int bx = blockIdx.x;
  int seg = 0;
#pragma unroll
  for (int i = 1; i < 4; ++i) seg += (bx >= a.cum[i]) ? 1 : 0;
  const int off = (bx - a.cum[seg]) * 256 + threadIdx.x;
  float4 f = reinterpret_cast<const float4*>(a.src[seg])[off];
  union { u16 u[4]; uint64_t q; } o;
  o.u[0] = f2b(f.x); o.u[1] = f2b(f.y); o.u[2] = f2b(f.z); o.u[3] = f2b(f.w);
  reinterpret_cast<uint64_t*>(a.dst[seg])[off] = o.q;
}

// ---------------------------------------------------------------- GEMM  C = A @ W^T + bias
// MODE 0 (R21): 128x64 tile, BK=32, 24KB LDS (linear), grid (16,32,3) ->
//   512 blocks/z = 6 co-resident blocks/CU. 4 waves: wr=w>>1 (64 rows),
//   wc=w&1 (32 cols); acc[4][2]. A = fp32 input (Q/K/V), fp32->bf16 fused
//   into staging (2-set reg pipeline + BARC(4)); per iter:
//     STAGEW(t+1)[1vm] -> ISSUE A(t+2)[4vm] -> MFMA(t) -> CVT A(t+1)
//     -> BARC(4): drains W(t+1), keeps A(t+2) in flight.
//   z==0 -> q (pre-scaled by log2(e)/sqrt(dk)); z==1 -> k; z==2 -> VT
//   [B,H,dk,S] with keys permuted (swap bits 2<->3 in 16-blocks).
// MODE 1 (R20): 64x128 tile, BK=64, XOR-8, 2-buffer; grid (8,64) = 512
//   blocks = 2 co-resident blocks/CU. Each of 4 waves computes 64x32.
template <int MODE>
__global__ __launch_bounds__(256, (MODE == 0) ? 6 : 2)
void gemm_bt(const float* __restrict__ Aq,
             const float* __restrict__ Ak,
             const float* __restrict__ Av,
             const u16* __restrict__ Abf,
             const u16* __restrict__ Wbase,
             const float* __restrict__ bias0,
             const float* __restrict__ bias1,
             const float* __restrict__ bias2,
             u16* __restrict__ outb,
             u16* __restrict__ vtout,
             float* __restrict__ outf) {
  constexpr int ASZ = 4096;                         // A buffer elems (both modes)
  constexpr int BSZ = (MODE == 0) ? 2048 : 8192;    // W buffer elems
  __shared__ u16 As[2][ASZ];
  __shared__ u16 Bs[2][BSZ];
  const int tid = threadIdx.x;
  const int lane = tid & 63;
  const int w = tid >> 6;
  const int wr = w >> 1, wc = w & 1;

  // T1: XCD-aware bijective swizzle.
  // MODE0: nwg=512/z (gridDim.x=16); MODE1: nwg=512 (gridDim.x=8).
  const int bid = (MODE == 0) ? blockIdx.y * 16 + blockIdx.x
                              : blockIdx.y * 8 + blockIdx.x;
  const int sw = (bid & 7) * 64 + (bid >> 3);
  const int n0 = (MODE == 0) ? (sw & 15) * 64 : (sw & 7) * 128;
  const int m0 = (MODE == 0) ? (sw >> 4) * 128 : (sw >> 3) * 64;
  const int z = (MODE == 0) ? blockIdx.z : 0;
  const float QSC = 0.18033688011112042f;  // log2(e) / sqrt(dk)

  const float* Af = (MODE == 0) ? (z == 0 ? Aq : (z == 1 ? Ak : Av)) : nullptr;
  const u16* W = Wbase + (size_t)z * (1024u * 1024u);
  const float* bias = (MODE == 0) ? (z == 0 ? bias0 : (z == 1 ? bias1 : bias2)) : bias0;
  u16* ob = (MODE == 0) ? (outb + (size_t)z * (4096u * 1024u)) : nullptr;

  const int l15 = lane & 15, l4 = lane >> 4;

  f32x4 acc[4][4];   // MODE0 uses [4][2]; MODE1 uses [4][2] as well
#pragma unroll
  for (int i = 0; i < 4; ++i)
#pragma unroll
    for (int j = 0; j < 4; ++j) acc[i][j] = {0.f, 0.f, 0.f, 0.f};

  if (MODE == 0) {
    // staging geometry (BK=32, linear): A: wave w stages rows [w*32,w*32+32)
    // as 2 calls of 16 rows; W: wave w stages rows [w*16,w*16+16) as 1 call.
    // per lane: row = base + lane/4, chunk = lane&3 (8 elems).
    const int sr2 = lane >> 2;
    const int sx2 = lane & 3;
    const float* gAf[2];
#pragma unroll
    for (int j = 0; j < 2; ++j)
      gAf[j] = Af + (size_t)(m0 + w * 32 + j * 16 + sr2) * 1024 + sx2 * 8;
    const u16* gB = W + (size_t)(n0 + w * 16 + sr2) * 1024 + sx2 * 8;

    auto STAGEW = [&](int kt, u16* bbuf) {
      stage16(gB + kt, &bbuf[(w * 16) * 32]);
    };

    // two A register sets: E holds even tiles, O holds odd tiles
    float4 e0[2], e1[2], o0[2], o1[2];
    auto ISSUE_E = [&](int kt) {
#pragma unroll
      for (int j = 0; j < 2; ++j) { e0[j] = *(const float4*)(gAf[j] + kt);
                                    e1[j] = *(const float4*)(gAf[j] + kt + 4); }
    };
    auto ISSUE_O = [&](int kt) {
#pragma unroll
      for (int j = 0; j < 2; ++j) { o0[j] = *(const float4*)(gAf[j] + kt);
                                    o1[j] = *(const float4*)(gAf[j] + kt + 4); }
    };
    auto CVT_E = [&](u16* abuf) {
#pragma unroll
      for (int j = 0; j < 2; ++j) {
        union { uint32_t d[4]; s16x8 v; } cv;
        cv.d[0] = cvtpk(e0[j].x, e0[j].y); cv.d[1] = cvtpk(e0[j].z, e0[j].w);
        cv.d[2] = cvtpk(e1[j].x, e1[j].y); cv.d[3] = cvtpk(e1[j].z, e1[j].w);
        *(s16x8*)&abuf[(w * 32 + j * 16) * 32 + lane * 8] = cv.v;
      }
    };
    auto CVT_O = [&](u16* abuf) {
#pragma unroll
      for (int j = 0; j < 2; ++j) {
        union { uint32_t d[4]; s16x8 v; } cv;
        cv.d[0] = cvtpk(o0[j].x, o0[j].y); cv.d[1] = cvtpk(o0[j].z, o0[j].w);
        cv.d[2] = cvtpk(o1[j].x, o1[j].y); cv.d[3] = cvtpk(o1[j].z, o1[j].w);
        *(s16x8*)&abuf[(w * 32 + j * 16) * 32 + lane * 8] = cv.v;
      }
    };
    auto MFMA = [&](const u16* abuf, const u16* bbuf) {
      s16x8 af[4], bf[2];
#pragma unroll
      for (int mi = 0; mi < 4; ++mi)
        af[mi] = *(const s16x8*)&abuf[(wr * 64 + mi * 16 + l15) * 32 + l4 * 8];
#pragma unroll
      for (int ni = 0; ni < 2; ++ni)
        bf[ni] = *(const s16x8*)&bbuf[(wc * 32 + ni * 16 + l15) * 32 + l4 * 8];
      __builtin_amdgcn_s_setprio(1);
#pragma unroll
      for (int mi = 0; mi < 4; ++mi)
#pragma unroll
        for (int ni = 0; ni < 2; ++ni)
          acc[mi][ni] = mfma16(af[mi], bf[ni], acc[mi][ni]);
      __builtin_amdgcn_s_setprio(0);
    };

    // prologue: W0 staged; A0,A1 issued; A0 cvt'd (waits A0, A1 stays).
    STAGEW(0, Bs[0]);
    ISSUE_E(0);
    ISSUE_O(32);
    CVT_E(As[0]);
    BARC(4);                       // drain W0; keep A1's 4 loads in flight

    // t = 0..29 (15 double-iters)
    for (int it = 0; it < 15; ++it) {
      const int t = 2 * it;
      STAGEW((t + 1) * 32, Bs[1]);
      ISSUE_E((t + 2) * 32);
      MFMA(As[0], Bs[0]);
      CVT_O(As[1]);                // waits A(t+1)
      BARC(4);                     // drain W(t+1); keep A(t+2)
      STAGEW((t + 2) * 32, Bs[0]);
      ISSUE_O((t + 3) * 32);
      MFMA(As[1], Bs[1]);
      CVT_E(As[0]);                // waits A(t+2)
      BARC(4);                     // drain W(t+2); keep A(t+3)
    }
    // t = 30: no more A issues; stage W31; cvt A31; full drain.
    STAGEW(31 * 32, Bs[1]);
    MFMA(As[0], Bs[0]);
    CVT_O(As[1]);
    BARC(0);                       // drain W31
    // t = 31
    MFMA(As[1], Bs[1]);
  } else {
    // ---- MODE 1: 64x128 tile, BK=64, XOR-8 swizzle, stage16 A+W, 2-buffer.
    const int sr = lane >> 3;
    const int sx = lane & 7;
    const u16* gAb[2];
    const u16* gB[4];
#pragma unroll
    for (int j = 0; j < 2; ++j) {
      const int row = w * 16 + j * 8 + sr;
      const int lc = ((sx ^ (row & 7)) << 3);
      gAb[j] = Abf + (size_t)(m0 + row) * 1024 + lc;
    }
#pragma unroll
    for (int j = 0; j < 4; ++j) {
      const int row = w * 32 + j * 8 + sr;
      const int lc = ((sx ^ (row & 7)) << 3);
      gB[j] = W + (size_t)(n0 + row) * 1024 + lc;
    }
#pragma unroll
    for (int j = 0; j < 2; ++j)
      stage16(gAb[j], &As[0][(w * 16 + j * 8) * 64]);
#pragma unroll
    for (int j = 0; j < 4; ++j)
      stage16(gB[j], &Bs[0][(w * 32 + j * 8) * 64]);
    __syncthreads();
#pragma unroll 2
    for (int t = 0; t < 16; ++t) {
      const int cur = t & 1;
      if (t + 1 < 16) {
        const int kt = (t + 1) * 64;
#pragma unroll
        for (int j = 0; j < 2; ++j)
          stage16(gAb[j] + kt, &As[cur ^ 1][(w * 16 + j * 8) * 64]);
#pragma unroll
        for (int j = 0; j < 4; ++j)
          stage16(gB[j] + kt, &Bs[cur ^ 1][(w * 32 + j * 8) * 64]);
      }
#pragma unroll
      for (int ks = 0; ks < 2; ++ks) {
        s16x8 af[4], bf[2];
#pragma unroll
        for (int mi = 0; mi < 4; ++mi) {
          const int row = mi * 16 + l15;
          const int sc_ = (((ks << 2) | l4) ^ (l15 & 7)) << 3;
          af[mi] = *(const s16x8*)&As[cur][row * 64 + sc_];
        }
#pragma unroll
        for (int ni = 0; ni < 2; ++ni) {
          const int row = w * 32 + ni * 16 + l15;
          const int sc_ = (((ks << 2) | l4) ^ (l15 & 7)) << 3;
          bf[ni] = *(const s16x8*)&Bs[cur][row * 64 + sc_];
        }
        __builtin_amdgcn_s_setprio(1);
#pragma unroll
        for (int mi = 0; mi < 4; ++mi)
#pragma unroll
          for (int ni = 0; ni < 2; ++ni)
            acc[mi][ni] = mfma16(af[mi], bf[ni], acc[mi][ni]);
        __builtin_amdgcn_s_setprio(0);
      }
      __syncthreads();
    }
  }

  if (MODE == 0) {
#pragma unroll
    for (int ni = 0; ni < 2; ++ni) {
      const int col = n0 + wc * 32 + ni * 16 + l15;
      const float bv = bias[col];
#pragma unroll
      for (int mi = 0; mi < 4; ++mi) {
        const int row0 = m0 + wr * 64 + mi * 16 + l4 * 4;
        if (z == 2) {
          // V -> VT [B,H,dk,S], permuted key order (swap bits 2<->3 of key idx)
          const int b = row0 >> 11, s0 = row0 & 2047;
          const int pos0 = (s0 & ~15) | ((s0 & 4) << 1) | ((s0 & 8) >> 1);
          const int h = col >> 6, d = col & 63;
          u16x4 pk = {f2b(acc[mi][ni][0] + bv), f2b(acc[mi][ni][1] + bv),
                      f2b(acc[mi][ni][2] + bv), f2b(acc[mi][ni][3] + bv)};
          *(u16x4*)&vtout[((size_t)(b * 16 + h) * 64 + d) * 2048 + pos0] = pk;
        } else {
#pragma unroll
          for (int r = 0; r < 4; ++r) {
            float val = acc[mi][ni][r] + bv;
            if (z == 0) val *= QSC;          // fold softmax scale into q
            const int row = row0 + r;
            const int b = row >> 11, s = row & 2047;
            const int h = col >> 6, d = col & 63;
            ob[((size_t)(b * 16 + h) * 2048 + s) * 64 + d] = f2b(val);
          }
        }
      }
    }
  } else {
#pragma unroll
    for (int ni = 0; ni < 2; ++ni) {
      const int col = n0 + w * 32 + ni * 16 + l15;
      const float bv = bias[col];
#pragma unroll
      for (int mi = 0; mi < 4; ++mi) {
        const int row0 = m0 + mi * 16 + l4 * 4;
#pragma unroll
        for (int r = 0; r < 4; ++r)
          outf[(size_t)(row0 + r) * 1024 + col] = acc[mi][ni][r] + bv;
      }
    }
  }
}

// ---------------------------------------------------------------- flash attention
// (Proven 51us body -- R8; frozen. All restructures were neutral/regressed.)
// 8 waves x 32 q = 256 q/block; grid (8,32) = 256 blocks = 1 block/CU.
// 32x32x16 MFMA: 16 MFMAs/iter (8 QK^T + 8 PV). Swapped QK^T: sc = mfma32(K,Q),
// D col = q = lane&31 (lane owns one q), 32 keys in regs. PV uses P straight
// from regs (VT key order permuted in global). Denominator = in-lane fp32
// adds + one shfl_xor(32). Running max baked into C-init; mrun starts 0;
// THR=8 defer-max rescale (rare).
__global__ __launch_bounds__(512, 2) void fattn(const u16* __restrict__ qp,
                                                const u16* __restrict__ kp,
                                                const u16* __restrict__ vt,
                                                u16* __restrict__ ao) {
  __shared__ u16 Kt[2][4096];               // 64 keys x 64 dk, chunk-swizzled
  __shared__ u16 Vt[2][4096];               // 64 d    x 64 keys (perm), chunk-swizzled

  const int lane = threadIdx.x & 63;
  const int w = threadIdx.x >> 6;           // 0..7
  const int bh = blockIdx.y;
  const int b = bh >> 4, h = bh & 15;
  const int q0 = blockIdx.x * 256 + w * 32;
  const u16* qb = qp + (size_t)bh * (2048 * 64);
  const u16* kb = kp + (size_t)bh * (2048 * 64);
  const u16* vb = vt + (size_t)bh * (64 * 2048);
  const int l31 = lane & 31, hl = lane >> 5;
  const int x7 = l31 & 7;                   // row&7 for all our LDS reads
  const float THR = 8.0f;                   // defer-max threshold (T13), log2 units

  // staging: wave w stages storage chunks [w*64, w*64+64) of each 8KB tile.
  // chunk s -> row s>>3, storage col s&7, logical col = (s&7) ^ (row&7).
  const int srow = (w << 3) + (lane >> 3);
  const int c0 = (((lane & 7) ^ (srow & 7)) << 3);   // logical col in elements

  // Q fragments (persistent): B-operand of 32x32x16: col = q = l31,
  // k-slot (hl,j) = dk kc*16 + hl*8 + j. q pre-scaled by log2(e)/sqrt(dk).
  s16x8 qa[4];
#pragma unroll
  for (int kc = 0; kc < 4; ++kc)
    qa[kc] = ld_g16(qb + (size_t)(q0 + l31) * 64 + kc * 16 + hl * 8);

  f32x16 o[2];                              // O[q=(reg&3)+8*(reg>>2)+4hl][d=dt*32+l31]
  float lsum = 0.f;                         // denominator for q = l31 (own keys)
  float mrun = 0.f;                         // running max for q = l31
#pragma unroll
  for (int r = 0; r < 16; ++r) { o[0][r] = 0.f; o[1][r] = 0.f; }

  // prologue: stage tile 0
  stage16(kb + (size_t)srow * 64 + c0, &Kt[0][w * 512]);
  stage16(vb + (size_t)srow * 2048 + c0, &Vt[0][w * 512]);
  __syncthreads();

#pragma unroll 2
  for (int t = 0; t < 32; ++t) {
    const int cur = t & 1;
    if (t + 1 < 32) {                       // issue next tile early
      const int kk = (t + 1) << 6;
      stage16(kb + (size_t)(kk + srow) * 64 + c0, &Kt[cur ^ 1][w * 512]);
      stage16(vb + (size_t)srow * 2048 + kk + c0, &Vt[cur ^ 1][w * 512]);
    }

    // ---- QK^T (swapped, 32x32x16): sc[nk] = D[key][q] - mrun (C-init bake)
    f32x16 sc[2];
#pragma unroll
    for (int r = 0; r < 16; ++r) { sc[0][r] = -mrun; sc[1][r] = -mrun; }
#pragma unroll
    for (int nk = 0; nk < 2; ++nk) {
      s16x8 kf[4];
#pragma unroll
      for (int kc = 0; kc < 4; ++kc)
        kf[kc] = *(const s16x8*)&Kt[cur][(nk * 32 + l31) * 64 +
                                         ((((kc << 1) | hl) ^ x7) << 3)];
      __builtin_amdgcn_s_setprio(1);
#pragma unroll
      for (int kc = 0; kc < 4; ++kc)
        sc[nk] = mfma32(kf[kc], qa[kc], sc[nk]);
      __builtin_amdgcn_s_setprio(0);
    }

    // ---- per-q relative max: in-lane over 32, then xor 32 (other key half)
    float m = -1e30f;
#pragma unroll
    for (int nk = 0; nk < 2; ++nk)
#pragma unroll
      for (int r = 0; r < 16; r += 2)
        m = max3f(m, sc[nk][r], sc[nk][r + 1]);
    m = fmaxf(m, __shfl_xor(m, 32));

    // ---- defer-max (T13): rare; uniform in-place correction
    if (__any(m > THR)) {
      const float d = fmaxf(m, 0.f);
      mrun += d;
      const float alpha = EXP2F(-d);
      lsum *= alpha;
#pragma unroll
      for (int r = 0; r < 16; ++r) { sc[0][r] -= d; sc[1][r] -= d; }
#pragma unroll
      for (int r = 0; r < 16; ++r) {
        float ar = __shfl(alpha, (r & 3) + 8 * (r >> 2) + 4 * hl);
        o[0][r] *= ar; o[1][r] *= ar;
      }
    }

    // ---- P = exp2(sc), denominator adds, pack regs -> PV MFMA
#pragma unroll
    for (int nk = 0; nk < 2; ++nk) {
      float p[16];
#pragma unroll
      for (int r = 0; r < 16; ++r) p[r] = EXP2F(sc[nk][r]);
#pragma unroll
      for (int r = 0; r < 16; ++r) lsum += p[r];
#pragma unroll
      for (int kc = 0; kc < 2; ++kc) {
        union { uint32_t d[4]; s16x8 v; } pa;
        pa.d[0] = cvtpk(p[kc * 8 + 0], p[kc * 8 + 1]);
        pa.d[1] = cvtpk(p[kc * 8 + 2], p[kc * 8 + 3]);
        pa.d[2] = cvtpk(p[kc * 8 + 4], p[kc * 8 + 5]);
        pa.d[3] = cvtpk(p[kc * 8 + 6], p[kc * 8 + 7]);
        const int chunk = nk * 4 + kc * 2 + hl;
#pragma unroll
        for (int dt = 0; dt < 2; ++dt) {
          s16x8 vf = *(const s16x8*)&Vt[cur][(dt * 32 + l31) * 64 +
                                             ((chunk ^ x7) << 3)];
          __builtin_amdgcn_s_setprio(1);
          o[dt] = mfma32(pa.v, vf, o[dt]);
          __builtin_amdgcn_s_setprio(0);
        }
      }
    }

    __syncthreads();   // all reads of buf `cur` done; next-tile stage drained
  }

  // ---- epilogue: combine denominator halves, normalize, store
  lsum += __shfl_xor(lsum, 32);
#pragma unroll
  for (int r = 0; r < 16; ++r) {
    const int qreg = (r & 3) + 8 * (r >> 2) + 4 * hl;
    const float inv = 1.0f / __shfl(lsum, qreg);
    const int row = b * 2048 + q0 + qreg;
#pragma unroll
    for (int dt = 0; dt < 2; ++dt)
      ao[(size_t)row * 1024 + h * 64 + dt * 32 + l31] = f2b(o[dt][r] * inv);
  }
}

// ---------------------------------------------------------------- host
extern "C" void kernel_launch(void* const* d_in, const int* in_sizes, int n_in,
                              void* d_out, int out_size, void* d_ws, size_t ws_size,
                              hipStream_t stream) {
  const float* Q  = (const float*)d_in[0];
  const float* K  = (const float*)d_in[1];
  const float* V  = (const float*)d_in[2];
  const float* Wq = (const float*)d_in[3];
  const float* bq = (const float*)d_in[4];
  const float* Wk = (const float*)d_in[5];
  const float* bk = (const float*)d_in[6];
  const float* Wv = (const float*)d_in[7];
  const float* bv = (const float*)d_in[8];
  const float* Wo = (const float*)d_in[9];
  const float* bo = (const float*)d_in[10];
  float* out = (float*)d_out;

  const size_t NI = (size_t)4096 * 1024;
  const size_t NW = (size_t)1024 * 1024;
  u16* WB  = (u16*)d_ws;          // Wq,Wk,Wv,Wo bf16 (4*NW)
  u16* QKV = WB + 4 * NW;         // q,k [B,H,S,dk] bf16 (slot 2 unused)
  u16* VT  = QKV + 3 * NI;        // vT [B,H,dk,S] bf16 (key-permuted)
  u16* AO  = VT + NI;             // attention output bf16 [B*S][D]

  CvtArgs ca;
  ca.src[0] = Wq; ca.dst[0] = WB;
  ca.src[1] = Wk; ca.dst[1] = WB + NW;
  ca.src[2] = Wv; ca.dst[2] = WB + 2 * NW;
  ca.src[3] = Wo; ca.dst[3] = WB + 3 * NW;
  ca.cum[0] = 0; ca.cum[1] = 1024; ca.cum[2] = 2048; ca.cum[3] = 3072; ca.cum[4] = 4096;
  cvt_all<<<dim3(4096), 256, 0, stream>>>(ca);

  // q,k,v projections (128x64 tiles -> 512 blocks/z = 6 blocks/CU);
  // z==0 pre-scales q; z==2 writes permuted VT
  gemm_bt<0><<<dim3(16, 32, 3), 256, 0, stream>>>(Q, K, V, nullptr, WB, bq, bk, bv,
                                                  QKV, VT, nullptr);
  // attention
  fattn<<<dim3(8, 32), 512, 0, stream>>>(QKV, QKV + NI, VT, AO);
  // output projection (64x128 tiles -> 512 blocks = 2 blocks/CU)
  gemm_bt<1><<<dim3(8, 64), 256, 0, stream>>>(nullptr, nullptr, nullptr, AO,
                                              WB + 3 * NW, bo, nullptr, nullptr,
                                              nullptr, nullptr, out);
}

// Round 22
// 110.443 us; speedup vs baseline: 2.4699x; 2.4699x over previous
//
#include <hip/hip_runtime.h>
#include <stdint.h>

// MultiHeadAttention fused pipeline for MI355X (gfx950).
// B=2, S=2048, D=1024, H=16, dk=64. fp32 in/out, bf16 MFMA compute.
// FINAL: R20 build (111.2us, best measured).
// - gemm MODE0: 128x128, BK=32, 32KB linear LDS, 3 blocks/CU co-resident,
//   fused fp32->bf16 A staging (2-set reg pipeline + BARC(4)).
// - gemm MODE1: 64x128, BK=64, XOR-8, 512 blocks = 2 blocks/CU.
// - fattn: frozen R8 body (8 waves x 32q, 32x32 MFMA, in-register P).
// - weights-only cvt.
// R21's 128x64 MODE0 retile (6 blocks/CU) destroyed A-reuse -> L3 thrash
// (FETCH 334MB, 272us): co-residency trades reuse for overlap; 128x128@3 is
// the measured optimum of that tradeoff.

#define AS1 __attribute__((address_space(1)))
#define AS3 __attribute__((address_space(3)))

typedef unsigned short u16;
typedef short s16x8 __attribute__((ext_vector_type(8)));   // 8 bf16 (4 VGPRs) MFMA frag
typedef float f32x4 __attribute__((ext_vector_type(4)));   // 16x16 MFMA accumulator
typedef float f32x16 __attribute__((ext_vector_type(16))); // 32x32 MFMA accumulator
typedef u16   u16x4 __attribute__((ext_vector_type(4)));

#if defined(__has_builtin)
#if __has_builtin(__builtin_amdgcn_exp2f)
#define EXP2F(x) __builtin_amdgcn_exp2f(x)
#else
#define EXP2F(x) exp2f(x)
#endif
#else
#define EXP2F(x) exp2f(x)
#endif

// Counted-vmcnt barrier (T4): keeps the N newest vmem ops in flight across
// the barrier instead of __syncthreads()' full vmcnt(0) drain.
#define BARC(N)                                                               \
  do {                                                                        \
    __builtin_amdgcn_sched_barrier(0);                                        \
    asm volatile("s_waitcnt vmcnt(" #N ") lgkmcnt(0)" ::: "memory");          \
    __builtin_amdgcn_s_barrier();                                             \
    __builtin_amdgcn_sched_barrier(0);                                        \
  } while (0)

__device__ __forceinline__ u16 f2b(float f) {  // fp32 -> bf16 RNE
  union { float f; uint32_t u; } v;
  v.f = f;
  uint32_t r = (v.u + 0x7fffu + ((v.u >> 16) & 1u)) >> 16;
  return (u16)r;
}

// packed fp32x2 -> bf16x2 (1 VALU op; no builtin on gfx950 -> inline asm, T12)
__device__ __forceinline__ uint32_t cvtpk(float lo, float hi) {
  uint32_t r;
  asm("v_cvt_pk_bf16_f32 %0, %1, %2" : "=v"(r) : "v"(lo), "v"(hi));
  return r;
}

__device__ __forceinline__ float max3f(float a, float b, float c) {
  float r;
  asm("v_max3_f32 %0, %1, %2, %3" : "=v"(r) : "v"(a), "v"(b), "v"(c));
  return r;
}

__device__ __forceinline__ f32x4 mfma16(s16x8 a, s16x8 b, f32x4 c) {
  return __builtin_amdgcn_mfma_f32_16x16x32_bf16(a, b, c, 0, 0, 0);
}

__device__ __forceinline__ f32x16 mfma32(s16x8 a, s16x8 b, f32x16 c) {
  return __builtin_amdgcn_mfma_f32_32x32x16_bf16(a, b, c, 0, 0, 0);
}

__device__ __forceinline__ s16x8 ld_g16(const u16* p) {
  return *reinterpret_cast<const s16x8*>(p);
}

// async global->LDS, 16B per lane. LDS dest must be WAVE-UNIFORM base; HW adds lane*16.
// Global SOURCE is per-lane -> swizzled layouts via pre-swizzled source (m173).
__device__ __forceinline__ void stage16(const u16* g, u16* lds_base) {
  __builtin_amdgcn_global_load_lds((const AS1 unsigned int*)g,
                                   (AS3 unsigned int*)lds_base, 16, 0, 0);
}

// ---------------------------------------------------------------- fp32 -> bf16 (weights only)
struct CvtArgs {
  const float* src[4];
  u16* dst[4];
  int cum[5];   // cumulative block ranges (1024 blocks per 1M-elem weight)
};

__global__ __launch_bounds__(256) void cvt_all(CvtArgs a) {
  const int bx = blockIdx.x;
  int seg = 0;
#pragma unroll
  for (int i = 1; i < 4; ++i) seg += (bx >= a.cum[i]) ? 1 : 0;
  const int off = (bx - a.cum[seg]) * 256 + threadIdx.x;
  float4 f = reinterpret_cast<const float4*>(a.src[seg])[off];
  union { u16 u[4]; uint64_t q; } o;
  o.u[0] = f2b(f.x); o.u[1] = f2b(f.y); o.u[2] = f2b(f.z); o.u[3] = f2b(f.w);
  reinterpret_cast<uint64_t*>(a.dst[seg])[off] = o.q;
}

// ---------------------------------------------------------------- GEMM  C = A @ W^T + bias
// MODE 0 (m97-shape): 128x128 tile, BK=32, 32KB LDS (linear), 3 blocks/CU
//   co-resident. A = fp32 input (Q/K/V), fp32->bf16 fused into staging with a
//   3-deep register pipeline + counted-vmcnt barriers:
//     iter t: STAGEW(t+1)[2vm] -> issue A(t+2)[4vm] -> MFMA(t)
//             -> cvt A(t+1) [implicit vmcnt(6)] -> BARC(4).
//   z==0 -> q (pre-scaled by log2(e)/sqrt(dk)); z==1 -> k; z==2 -> VT
//   [B,H,dk,S] with keys permuted (swap bits 2<->3 in 16-blocks).
// MODE 1: 64x128 tile, BK=64, XOR-8, 2-buffer; grid (8,64) = 512 blocks
//   = 2 co-resident blocks/CU. Each of 4 waves computes 64x32.
template <int MODE>
__global__ __launch_bounds__(256, (MODE == 0) ? 3 : 2)
void gemm_bt(const float* __restrict__ Aq,
             const float* __restrict__ Ak,
             const float* __restrict__ Av,
             const u16* __restrict__ Abf,
             const u16* __restrict__ Wbase,
             const float* __restrict__ bias0,
             const float* __restrict__ bias1,
             const float* __restrict__ bias2,
             u16* __restrict__ outb,
             u16* __restrict__ vtout,
             float* __restrict__ outf) {
  constexpr int ASZ = 4096;                         // A buffer elems (both modes)
  constexpr int BSZ = (MODE == 0) ? 4096 : 8192;    // W buffer elems
  __shared__ u16 As[2][ASZ];
  __shared__ u16 Bs[2][BSZ];
  const int tid = threadIdx.x;
  const int lane = tid & 63;
  const int w = tid >> 6;
  const int wr = w >> 1, wc = w & 1;       // MODE0: 2x2 wave grid, each 64x64

  // T1: XCD-aware bijective swizzle. MODE0: nwg=256; MODE1: nwg=512 (both %8==0).
  const int bid = blockIdx.y * 8 + blockIdx.x;
  const int sw = (MODE == 0) ? (bid & 7) * 32 + (bid >> 3)
                             : (bid & 7) * 64 + (bid >> 3);
  const int n0 = (sw & 7) * 128;
  const int m0 = (MODE == 0) ? (sw >> 3) * 128 : (sw >> 3) * 64;
  const int z = (MODE == 0) ? blockIdx.z : 0;
  const float QSC = 0.18033688011112042f;  // log2(e) / sqrt(dk)

  const float* Af = (MODE == 0) ? (z == 0 ? Aq : (z == 1 ? Ak : Av)) : nullptr;
  const u16* W = Wbase + (size_t)z * (1024u * 1024u);
  const float* bias = (MODE == 0) ? (z == 0 ? bias0 : (z == 1 ? bias1 : bias2)) : bias0;
  u16* ob = (MODE == 0) ? (outb + (size_t)z * (4096u * 1024u)) : nullptr;

  const int l15 = lane & 15, l4 = lane >> 4;

  f32x4 acc[4][4];
#pragma unroll
  for (int i = 0; i < 4; ++i)
#pragma unroll
    for (int j = 0; j < 4; ++j) acc[i][j] = {0.f, 0.f, 0.f, 0.f};

  if (MODE == 0) {
    // staging geometry (BK=32, linear): call j in {0,1}:
    // row = w*32 + j*16 + lane/4, chunk = lane&3 (8 elems).
    const int sr2 = lane >> 2;
    const int sx2 = lane & 3;
    const float* gAf[2];
    const u16* gB[2];
#pragma unroll
    for (int j = 0; j < 2; ++j) {
      const int row = w * 32 + j * 16 + sr2;
      gAf[j] = Af + (size_t)(m0 + row) * 1024 + sx2 * 8;
      gB[j]  = W + (size_t)(n0 + row) * 1024 + sx2 * 8;
    }

    auto STAGEW = [&](int kt, u16* bbuf) {
#pragma unroll
      for (int j = 0; j < 2; ++j)
        stage16(gB[j] + kt, &bbuf[(w * 32 + j * 16) * 32]);
    };

    // two A register sets: E holds even tiles, O holds odd tiles
    float4 e0[2], e1[2], o0[2], o1[2];
    auto ISSUE_E = [&](int kt) {
#pragma unroll
      for (int j = 0; j < 2; ++j) { e0[j] = *(const float4*)(gAf[j] + kt);
                                    e1[j] = *(const float4*)(gAf[j] + kt + 4); }
    };
    auto ISSUE_O = [&](int kt) {
#pragma unroll
      for (int j = 0; j < 2; ++j) { o0[j] = *(const float4*)(gAf[j] + kt);
                                    o1[j] = *(const float4*)(gAf[j] + kt + 4); }
    };
    auto CVT_E = [&](u16* abuf) {
#pragma unroll
      for (int j = 0; j < 2; ++j) {
        union { uint32_t d[4]; s16x8 v; } cv;
        cv.d[0] = cvtpk(e0[j].x, e0[j].y); cv.d[1] = cvtpk(e0[j].z, e0[j].w);
        cv.d[2] = cvtpk(e1[j].x, e1[j].y); cv.d[3] = cvtpk(e1[j].z, e1[j].w);
        *(s16x8*)&abuf[(w * 32 + j * 16) * 32 + lane * 8] = cv.v;
      }
    };
    auto CVT_O = [&](u16* abuf) {
#pragma unroll
      for (int j = 0; j < 2; ++j) {
        union { uint32_t d[4]; s16x8 v; } cv;
        cv.d[0] = cvtpk(o0[j].x, o0[j].y); cv.d[1] = cvtpk(o0[j].z, o0[j].w);
        cv.d[2] = cvtpk(o1[j].x, o1[j].y); cv.d[3] = cvtpk(o1[j].z, o1[j].w);
        *(s16x8*)&abuf[(w * 32 + j * 16) * 32 + lane * 8] = cv.v;
      }
    };
    auto MFMA = [&](const u16* abuf, const u16* bbuf) {
      s16x8 af[4], bf[4];
#pragma unroll
      for (int mi = 0; mi < 4; ++mi)
        af[mi] = *(const s16x8*)&abuf[(wr * 64 + mi * 16 + l15) * 32 + l4 * 8];
#pragma unroll
      for (int ni = 0; ni < 4; ++ni)
        bf[ni] = *(const s16x8*)&bbuf[(wc * 64 + ni * 16 + l15) * 32 + l4 * 8];
      __builtin_amdgcn_s_setprio(1);
#pragma unroll
      for (int mi = 0; mi < 4; ++mi)
#pragma unroll
        for (int ni = 0; ni < 4; ++ni)
          acc[mi][ni] = mfma16(af[mi], bf[ni], acc[mi][ni]);
      __builtin_amdgcn_s_setprio(0);
    };

    // prologue: W0 staged; A0,A1 issued; A0 cvt'd (waits A0, A1 stays).
    STAGEW(0, Bs[0]);
    ISSUE_E(0);
    ISSUE_O(32);
    CVT_E(As[0]);
    BARC(4);                       // drain W0; keep A1's 4 loads in flight

    // t = 0..29 (15 double-iters)
    for (int it = 0; it < 15; ++it) {
      const int t = 2 * it;
      STAGEW((t + 1) * 32, Bs[1]);
      ISSUE_E((t + 2) * 32);
      MFMA(As[0], Bs[0]);
      CVT_O(As[1]);                // waits A(t+1): implicit vmcnt(6)
      BARC(4);                     // drain W(t+1); keep A(t+2)
      STAGEW((t + 2) * 32, Bs[0]);
      ISSUE_O((t + 3) * 32);
      MFMA(As[1], Bs[1]);
      CVT_E(As[0]);                // waits A(t+2): implicit vmcnt(6)
      BARC(4);                     // drain W(t+2); keep A(t+3)
    }
    // t = 30: no more A issues; stage W31; cvt A31; full drain.
    STAGEW(31 * 32, Bs[1]);
    MFMA(As[0], Bs[0]);
    CVT_O(As[1]);                  // waits A31 (implicit vmcnt(2))
    BARC(0);                       // drain W31
    // t = 31
    MFMA(As[1], Bs[1]);
  } else {
    // ---- MODE 1: 64x128 tile, BK=64, XOR-8 swizzle, stage16 A+W, 2-buffer.
    // Each of 4 waves computes the full 64 rows x its own 32 cols.
    const int sr = lane >> 3;
    const int sx = lane & 7;
    const u16* gAb[2];
    const u16* gB[4];
#pragma unroll
    for (int j = 0; j < 2; ++j) {
      const int row = w * 16 + j * 8 + sr;
      const int lc = ((sx ^ (row & 7)) << 3);
      gAb[j] = Abf + (size_t)(m0 + row) * 1024 + lc;
    }
#pragma unroll
    for (int j = 0; j < 4; ++j) {
      const int row = w * 32 + j * 8 + sr;
      const int lc = ((sx ^ (row & 7)) << 3);
      gB[j] = W + (size_t)(n0 + row) * 1024 + lc;
    }
#pragma unroll
    for (int j = 0; j < 2; ++j)
      stage16(gAb[j], &As[0][(w * 16 + j * 8) * 64]);
#pragma unroll
    for (int j = 0; j < 4; ++j)
      stage16(gB[j], &Bs[0][(w * 32 + j * 8) * 64]);
    __syncthreads();
#pragma unroll 2
    for (int t = 0; t < 16; ++t) {
      const int cur = t & 1;
      if (t + 1 < 16) {
        const int kt = (t + 1) * 64;
#pragma unroll
        for (int j = 0; j < 2; ++j)
          stage16(gAb[j] + kt, &As[cur ^ 1][(w * 16 + j * 8) * 64]);
#pragma unroll
        for (int j = 0; j < 4; ++j)
          stage16(gB[j] + kt, &Bs[cur ^ 1][(w * 32 + j * 8) * 64]);
      }
#pragma unroll
      for (int ks = 0; ks < 2; ++ks) {
        s16x8 af[4], bf[2];
#pragma unroll
        for (int mi = 0; mi < 4; ++mi) {
          const int row = mi * 16 + l15;
          const int sc_ = (((ks << 2) | l4) ^ (l15 & 7)) << 3;
          af[mi] = *(const s16x8*)&As[cur][row * 64 + sc_];
        }
#pragma unroll
        for (int ni = 0; ni < 2; ++ni) {
          const int row = w * 32 + ni * 16 + l15;
          const int sc_ = (((ks << 2) | l4) ^ (l15 & 7)) << 3;
          bf[ni] = *(const s16x8*)&Bs[cur][row * 64 + sc_];
        }
        __builtin_amdgcn_s_setprio(1);
#pragma unroll
        for (int mi = 0; mi < 4; ++mi)
#pragma unroll
          for (int ni = 0; ni < 2; ++ni)
            acc[mi][ni] = mfma16(af[mi], bf[ni], acc[mi][ni]);
        __builtin_amdgcn_s_setprio(0);
      }
      __syncthreads();
    }
  }

  if (MODE == 0) {
#pragma unroll
    for (int ni = 0; ni < 4; ++ni) {
      const int col = n0 + wc * 64 + ni * 16 + l15;
      const float bv = bias[col];
#pragma unroll
      for (int mi = 0; mi < 4; ++mi) {
        const int row0 = m0 + wr * 64 + mi * 16 + l4 * 4;
        if (z == 2) {
          // V -> VT [B,H,dk,S], permuted key order (swap bits 2<->3 of key idx)
          const int b = row0 >> 11, s0 = row0 & 2047;
          const int pos0 = (s0 & ~15) | ((s0 & 4) << 1) | ((s0 & 8) >> 1);
          const int h = col >> 6, d = col & 63;
          u16x4 pk = {f2b(acc[mi][ni][0] + bv), f2b(acc[mi][ni][1] + bv),
                      f2b(acc[mi][ni][2] + bv), f2b(acc[mi][ni][3] + bv)};
          *(u16x4*)&vtout[((size_t)(b * 16 + h) * 64 + d) * 2048 + pos0] = pk;
        } else {
#pragma unroll
          for (int r = 0; r < 4; ++r) {
            float val = acc[mi][ni][r] + bv;
            if (z == 0) val *= QSC;          // fold softmax scale into q
            const int row = row0 + r;
            const int b = row >> 11, s = row & 2047;
            const int h = col >> 6, d = col & 63;
            ob[((size_t)(b * 16 + h) * 2048 + s) * 64 + d] = f2b(val);
          }
        }
      }
    }
  } else {
#pragma unroll
    for (int ni = 0; ni < 2; ++ni) {
      const int col = n0 + w * 32 + ni * 16 + l15;
      const float bv = bias[col];
#pragma unroll
      for (int mi = 0; mi < 4; ++mi) {
        const int row0 = m0 + mi * 16 + l4 * 4;
#pragma unroll
        for (int r = 0; r < 4; ++r)
          outf[(size_t)(row0 + r) * 1024 + col] = acc[mi][ni][r] + bv;
      }
    }
  }
}

// ---------------------------------------------------------------- flash attention
// (Proven 51us body -- R8; frozen. All restructures were neutral/regressed.)
// 8 waves x 32 q = 256 q/block; grid (8,32) = 256 blocks = 1 block/CU.
// 32x32x16 MFMA: 16 MFMAs/iter (8 QK^T + 8 PV). Swapped QK^T: sc = mfma32(K,Q),
// D col = q = lane&31 (lane owns one q), 32 keys in regs. PV uses P straight
// from regs (VT key order permuted in global). Denominator = in-lane fp32
// adds + one shfl_xor(32). Running max baked into C-init; mrun starts 0;
// THR=8 defer-max rescale (rare).
__global__ __launch_bounds__(512, 2) void fattn(const u16* __restrict__ qp,
                                                const u16* __restrict__ kp,
                                                const u16* __restrict__ vt,
                                                u16* __restrict__ ao) {
  __shared__ u16 Kt[2][4096];               // 64 keys x 64 dk, chunk-swizzled
  __shared__ u16 Vt[2][4096];               // 64 d    x 64 keys (perm), chunk-swizzled

  const int lane = threadIdx.x & 63;
  const int w = threadIdx.x >> 6;           // 0..7
  const int bh = blockIdx.y;
  const int b = bh >> 4, h = bh & 15;
  const int q0 = blockIdx.x * 256 + w * 32;
  const u16* qb = qp + (size_t)bh * (2048 * 64);
  const u16* kb = kp + (size_t)bh * (2048 * 64);
  const u16* vb = vt + (size_t)bh * (64 * 2048);
  const int l31 = lane & 31, hl = lane >> 5;
  const int x7 = l31 & 7;                   // row&7 for all our LDS reads
  const float THR = 8.0f;                   // defer-max threshold (T13), log2 units

  // staging: wave w stages storage chunks [w*64, w*64+64) of each 8KB tile.
  // chunk s -> row s>>3, storage col s&7, logical col = (s&7) ^ (row&7).
  const int srow = (w << 3) + (lane >> 3);
  const int c0 = (((lane & 7) ^ (srow & 7)) << 3);   // logical col in elements

  // Q fragments (persistent): B-operand of 32x32x16: col = q = l31,
  // k-slot (hl,j) = dk kc*16 + hl*8 + j. q pre-scaled by log2(e)/sqrt(dk).
  s16x8 qa[4];
#pragma unroll
  for (int kc = 0; kc < 4; ++kc)
    qa[kc] = ld_g16(qb + (size_t)(q0 + l31) * 64 + kc * 16 + hl * 8);

  f32x16 o[2];                              // O[q=(reg&3)+8*(reg>>2)+4hl][d=dt*32+l31]
  float lsum = 0.f;                         // denominator for q = l31 (own keys)
  float mrun = 0.f;                         // running max for q = l31
#pragma unroll
  for (int r = 0; r < 16; ++r) { o[0][r] = 0.f; o[1][r] = 0.f; }

  // prologue: stage tile 0
  stage16(kb + (size_t)srow * 64 + c0, &Kt[0][w * 512]);
  stage16(vb + (size_t)srow * 2048 + c0, &Vt[0][w * 512]);
  __syncthreads();

#pragma unroll 2
  for (int t = 0; t < 32; ++t) {
    const int cur = t & 1;
    if (t + 1 < 32) {                       // issue next tile early
      const int kk = (t + 1) << 6;
      stage16(kb + (size_t)(kk + srow) * 64 + c0, &Kt[cur ^ 1][w * 512]);
      stage16(vb + (size_t)srow * 2048 + kk + c0, &Vt[cur ^ 1][w * 512]);
    }

    // ---- QK^T (swapped, 32x32x16): sc[nk] = D[key][q] - mrun (C-init bake)
    f32x16 sc[2];
#pragma unroll
    for (int r = 0; r < 16; ++r) { sc[0][r] = -mrun; sc[1][r] = -mrun; }
#pragma unroll
    for (int nk = 0; nk < 2; ++nk) {
      s16x8 kf[4];
#pragma unroll
      for (int kc = 0; kc < 4; ++kc)
        kf[kc] = *(const s16x8*)&Kt[cur][(nk * 32 + l31) * 64 +
                                         ((((kc << 1) | hl) ^ x7) << 3)];
      __builtin_amdgcn_s_setprio(1);
#pragma unroll
      for (int kc = 0; kc < 4; ++kc)
        sc[nk] = mfma32(kf[kc], qa[kc], sc[nk]);
      __builtin_amdgcn_s_setprio(0);
    }

    // ---- per-q relative max: in-lane over 32, then xor 32 (other key half)
    float m = -1e30f;
#pragma unroll
    for (int nk = 0; nk < 2; ++nk)
#pragma unroll
      for (int r = 0; r < 16; r += 2)
        m = max3f(m, sc[nk][r], sc[nk][r + 1]);
    m = fmaxf(m, __shfl_xor(m, 32));

    // ---- defer-max (T13): rare; uniform in-place correction
    if (__any(m > THR)) {
      const float d = fmaxf(m, 0.f);
      mrun += d;
      const float alpha = EXP2F(-d);
      lsum *= alpha;
#pragma unroll
      for (int r = 0; r < 16; ++r) { sc[0][r] -= d; sc[1][r] -= d; }
#pragma unroll
      for (int r = 0; r < 16; ++r) {
        float ar = __shfl(alpha, (r & 3) + 8 * (r >> 2) + 4 * hl);
        o[0][r] *= ar; o[1][r] *= ar;
      }
    }

    // ---- P = exp2(sc), denominator adds, pack regs -> PV MFMA
#pragma unroll
    for (int nk = 0; nk < 2; ++nk) {
      float p[16];
#pragma unroll
      for (int r = 0; r < 16; ++r) p[r] = EXP2F(sc[nk][r]);
#pragma unroll
      for (int r = 0; r < 16; ++r) lsum += p[r];
#pragma unroll
      for (int kc = 0; kc < 2; ++kc) {
        union { uint32_t d[4]; s16x8 v; } pa;
        pa.d[0] = cvtpk(p[kc * 8 + 0], p[kc * 8 + 1]);
        pa.d[1] = cvtpk(p[kc * 8 + 2], p[kc * 8 + 3]);
        pa.d[2] = cvtpk(p[kc * 8 + 4], p[kc * 8 + 5]);
        pa.d[3] = cvtpk(p[kc * 8 + 6], p[kc * 8 + 7]);
        const int chunk = nk * 4 + kc * 2 + hl;
#pragma unroll
        for (int dt = 0; dt < 2; ++dt) {
          s16x8 vf = *(const s16x8*)&Vt[cur][(dt * 32 + l31) * 64 +
                                             ((chunk ^ x7) << 3)];
          __builtin_amdgcn_s_setprio(1);
          o[dt] = mfma32(pa.v, vf, o[dt]);
          __builtin_amdgcn_s_setprio(0);
        }
      }
    }

    __syncthreads();   // all reads of buf `cur` done; next-tile stage drained
  }

  // ---- epilogue: combine denominator halves, normalize, store
  lsum += __shfl_xor(lsum, 32);
#pragma unroll
  for (int r = 0; r < 16; ++r) {
    const int qreg = (r & 3) + 8 * (r >> 2) + 4 * hl;
    const float inv = 1.0f / __shfl(lsum, qreg);
    const int row = b * 2048 + q0 + qreg;
#pragma unroll
    for (int dt = 0; dt < 2; ++dt)
      ao[(size_t)row * 1024 + h * 64 + dt * 32 + l31] = f2b(o[dt][r] * inv);
  }
}

// ---------------------------------------------------------------- host
extern "C" void kernel_launch(void* const* d_in, const int* in_sizes, int n_in,
                              void* d_out, int out_size, void* d_ws, size_t ws_size,
                              hipStream_t stream) {
  const float* Q  = (const float*)d_in[0];
  const float* K  = (const float*)d_in[1];
  const float* V  = (const float*)d_in[2];
  const float* Wq = (const float*)d_in[3];
  const float* bq = (const float*)d_in[4];
  const float* Wk = (const float*)d_in[5];
  const float* bk = (const float*)d_in[6];
  const float* Wv = (const float*)d_in[7];
  const float* bv = (const float*)d_in[8];
  const float* Wo = (const float*)d_in[9];
  const float* bo = (const float*)d_in[10];
  float* out = (float*)d_out;

  const size_t NI = (size_t)4096 * 1024;
  const size_t NW = (size_t)1024 * 1024;
  u16* WB  = (u16*)d_ws;          // Wq,Wk,Wv,Wo bf16 (4*NW)
  u16* QKV = WB + 4 * NW;         // q,k [B,H,S,dk] bf16 (slot 2 unused)
  u16* VT  = QKV + 3 * NI;        // vT [B,H,dk,S] bf16 (key-permuted)
  u16* AO  = VT + NI;             // attention output bf16 [B*S][D]

  CvtArgs ca;
  ca.src[0] = Wq; ca.dst[0] = WB;
  ca.src[1] = Wk; ca.dst[1] = WB + NW;
  ca.src[2] = Wv; ca.dst[2] = WB + 2 * NW;
  ca.src[3] = Wo; ca.dst[3] = WB + 3 * NW;
  ca.cum[0] = 0; ca.cum[1] = 1024; ca.cum[2] = 2048; ca.cum[3] = 3072; ca.cum[4] = 4096;
  cvt_all<<<dim3(4096), 256, 0, stream>>>(ca);

  // q,k,v projections (z = 0,1,2) with fused fp32->bf16 A-staging;
  // z==0 pre-scales q; z==2 writes permuted VT
  gemm_bt<0><<<dim3(8, 32, 3), 256, 0, stream>>>(Q, K, V, nullptr, WB, bq, bk, bv,
                                                 QKV, VT, nullptr);
  // attention
  fattn<<<dim3(8, 32), 512, 0, stream>>>(QKV, QKV + NI, VT, AO);
  // output projection (64x128 tiles -> 512 blocks = 2 blocks/CU)
  gemm_bt<1><<<dim3(8, 64), 256, 0, stream>>>(nullptr, nullptr, nullptr, AO,
                                              WB + 3 * NW, bo, nullptr, nullptr,
                                              nullptr, nullptr, out);
}